// Round 1
// baseline (632.397 us; speedup 1.0000x reference)
//
#include <hip/hip_runtime.h>

// SelMul: out[b][k] = x[b][i] * x[b][j] for all i<=j in row-major upper-tri order.
// B=256, N=1024 -> out has N*(N+1)/2 = 524800 cols per row, 537 MB total fp32.
// Pure write-streaming problem: block per (i, b), contiguous coalesced output
// segment of length N-i, float4 stores after scalar-aligning the head.

#define N 1024
#define TRI (N * (N + 1) / 2)  // 524800, divisible by 4

__global__ __launch_bounds__(256) void selmul_kernel(const float* __restrict__ x,
                                                     float* __restrict__ out) {
    const int i = blockIdx.x;   // triangular row index, 0..N-1
    const int b = blockIdx.y;   // batch row
    const float* __restrict__ xrow = x + b * N;
    const float xi = xrow[i];

    const int tri_off = i * N - (i * (i - 1)) / 2;   // start of row i's segment
    float* __restrict__ o = out + (size_t)b * TRI + tri_off;
    const int len = N - i;
    const int tid = threadIdx.x;

    // Scalar head until the output pointer is 16B-aligned (TRI % 4 == 0, so
    // alignment is governed by tri_off mod 4; out base is >=256B aligned).
    int head = (4 - (tri_off & 3)) & 3;
    if (head > len) head = len;
    if (tid < head) o[tid] = xi * xrow[i + tid];

    const int len2 = len - head;
    const int nvec = len2 >> 2;
    const float* __restrict__ xv = xrow + i + head;
    float4* __restrict__ ov = (float4*)(o + head);

    for (int v = tid; v < nvec; v += 256) {
        const int j = v << 2;
        float4 r;
        r.x = xi * xv[j + 0];   // x loads are unaligned-offset scalars: all L1 hits
        r.y = xi * xv[j + 1];
        r.z = xi * xv[j + 2];
        r.w = xi * xv[j + 3];
        ov[v] = r;              // 16B coalesced store
    }

    const int rem = len2 & 3;
    if (tid < rem) {
        const int j = (nvec << 2) + tid;
        o[head + j] = xi * xv[j];
    }
}

extern "C" void kernel_launch(void* const* d_in, const int* in_sizes, int n_in,
                              void* d_out, int out_size, void* d_ws, size_t ws_size,
                              hipStream_t stream) {
    const float* x = (const float*)d_in[0];
    float* out = (float*)d_out;
    const int B = in_sizes[0] / N;   // 256
    dim3 grid(N, B);
    selmul_kernel<<<grid, 256, 0, stream>>>(x, out);
}

// Round 2
// 603.393 us; speedup vs baseline: 1.0481x; 1.0481x over previous
//
#include <hip/hip_runtime.h>

// SelMul: out[b][k] = x[b][i]*x[b][j], i<=j, row-major upper-tri. B=256, N=1024.
// 537 MB fp32 output -> pure write-streaming. Round-1 lesson: 262K tiny blocks
// were dispatch-bound (0.85 TB/s). Now: grid-stride over flat float4 indices,
// triangular-row inversion via one fp32 sqrt per float4 (exact: D < 2^23),
// 8192 blocks x 256 threads, ~16 float4/thread, 64 KB written per block.

#define N 1024
#define TRI (N * (N + 1) / 2)   // 524800
#define TRI4 (TRI / 4)          // 131200 float4s per batch row
#define TPB 256
#define NBLOCKS 8192

__global__ __launch_bounds__(TPB) void selmul_kernel(const float* __restrict__ x,
                                                     float* __restrict__ out,
                                                     int total4) {
    const int stride = gridDim.x * TPB;
    for (int v = blockIdx.x * TPB + threadIdx.x; v < total4; v += stride) {
        const int b = (int)((unsigned)v / TRI4);        // const-div -> magic mul
        const int r = (v - b * TRI4) << 2;              // elem offset within row, %4==0

        // Invert triangular offset: largest i with i*(2049-i)/2 <= r.
        // D = 2049^2 - 8r <= 4198401 < 2^23: exactly representable in fp32.
        const float s = sqrtf(4198401.0f - 8.0f * (float)r);
        int i = (int)((2049.0f - s) * 0.5f);
        int rs = (i * (2049 - i)) >> 1;                 // rowstart(i)
        if (rs > r) {                                   // fp floor overshoot
            --i;
            rs = (i * (2049 - i)) >> 1;
        } else {
            const int rs1 = ((i + 1) * (2048 - i)) >> 1; // rowstart(i+1)
            if (rs1 <= r) { ++i; rs = rs1; }
        }
        int j = i + (r - rs);

        const float* __restrict__ xrow = x + b * N;     // 4 KB, L1-resident
        float xi = xrow[i];
        float4 o;
        o.x = xi * xrow[j];
        if (++j >= N) { ++i; j = i; xi = xrow[i]; }     // row crossing (<=1 per float4)
        o.y = xi * xrow[j];
        if (++j >= N) { ++i; j = i; xi = xrow[i]; }
        o.z = xi * xrow[j];
        if (++j >= N) { ++i; j = i; xi = xrow[i]; }
        o.w = xi * xrow[j];

        ((float4*)out)[v] = o;                          // coalesced 16 B/lane store
    }
}

extern "C" void kernel_launch(void* const* d_in, const int* in_sizes, int n_in,
                              void* d_out, int out_size, void* d_ws, size_t ws_size,
                              hipStream_t stream) {
    const float* x = (const float*)d_in[0];
    float* out = (float*)d_out;
    const int total4 = out_size >> 2;   // out_size divisible by 4 (TRI % 4 == 0)
    selmul_kernel<<<NBLOCKS, TPB, 0, stream>>>(x, out, total4);
}